// Round 7
// baseline (520.778 us; speedup 1.0000x reference)
//
#include <hip/hip_runtime.h>

#define NUM_NODES 100000
#define EMB_DIM   64
#define NUM_LAYERS 3
#define NUM_EDGES 3200000
#define NUM_QUERY 1000000

#define BSHIFT   6
#define BNODES   64                                    // nodes per bucket
#define NBUCKETS ((NUM_NODES + BNODES - 1) / BNODES)   // 1563
#define SRC_MASK 131071                                // 17 bits (NUM_NODES < 2^17)
#define NCHUNK   128
#define CHUNK    (NUM_EDGES / NCHUNK)                  // 25000 edges per chunk

// ---------------------------------------------------------------------------
// Pass 1: per-chunk bucket histogram in LDS -> hist_g[chunk][bucket]
__global__ __launch_bounds__(256) void chist_kernel(const int* __restrict__ dst,
                                                    int* __restrict__ hist_g) {
    __shared__ int h[NBUCKETS];
    int b = blockIdx.x, tid = threadIdx.x;
    for (int k = tid; k < NBUCKETS; k += 256) h[k] = 0;
    __syncthreads();
    int beg = b * CHUNK, end = beg + CHUNK;
    for (int i = beg + tid; i < end; i += 256)
        atomicAdd(&h[dst[i] >> BSHIFT], 1);
    __syncthreads();
    for (int k = tid; k < NBUCKETS; k += 256)
        hist_g[b * NBUCKETS + k] = h[k];
}

// Per-bucket exclusive scan across the 128 chunks (one wave per bucket, in place).
// Also emits bucket totals.
__global__ void bscan_kernel(int* __restrict__ hist_g, int* __restrict__ bcnt) {
    int gw   = (blockIdx.x * blockDim.x + threadIdx.x) >> 6;
    int lane = threadIdx.x & 63;
    if (gw >= NBUCKETS) return;
    int c0 = 2 * lane, c1 = 2 * lane + 1;
    int v0 = hist_g[c0 * NBUCKETS + gw];
    int v1 = hist_g[c1 * NBUCKETS + gw];
    int pair = v0 + v1, x = pair;
    #pragma unroll
    for (int d = 1; d < 64; d <<= 1) {
        int y = __shfl_up(x, d);
        if (lane >= d) x += y;
    }
    int ex = x - pair;                    // exclusive prefix over chunks
    hist_g[c0 * NBUCKETS + gw] = ex;
    hist_g[c1 * NBUCKETS + gw] = ex + v0;
    if (lane == 63) bcnt[gw] = x;         // bucket total
}

// single-block scan over NBUCKETS (2 tiles): boffs[b+1] = inclusive sum
__global__ void scan_kernel(const int* __restrict__ bcnt, int* __restrict__ boffs) {
    __shared__ int tile[1024];
    __shared__ int carry;
    int t = threadIdx.x;
    if (t == 0) { carry = 0; boffs[0] = 0; }
    __syncthreads();
    for (int base = 0; base < NBUCKETS; base += 1024) {
        int v = (base + t < NBUCKETS) ? bcnt[base + t] : 0;
        tile[t] = v;
        __syncthreads();
        for (int d = 1; d < 1024; d <<= 1) {
            int add = (t >= d) ? tile[t - d] : 0;
            __syncthreads();
            tile[t] += add;
            __syncthreads();
        }
        int inc = tile[t] + carry;
        if (base + t < NBUCKETS) boffs[base + t + 1] = inc;
        __syncthreads();
        if (t == 1023) carry = inc;
        __syncthreads();
    }
}

// Pass 2: scatter via LDS cursors — every (chunk,bucket) segment is written by
// exactly one block (one XCD), killing cross-XCD line ping-pong.
__global__ __launch_bounds__(256) void cscatter_kernel(
        const int* __restrict__ src, const int* __restrict__ dst,
        const int* __restrict__ boffs, const int* __restrict__ hist_g,
        int* __restrict__ packed) {
    __shared__ int cur[NBUCKETS];
    int b = blockIdx.x, tid = threadIdx.x;
    for (int k = tid; k < NBUCKETS; k += 256)
        cur[k] = boffs[k] + hist_g[b * NBUCKETS + k];
    __syncthreads();
    int beg = b * CHUNK, end = beg + CHUNK;
    for (int i = beg + tid; i < end; i += 256) {
        int s = src[i], d = dst[i];
        int pos = atomicAdd(&cur[d >> BSHIFT], 1);
        packed[pos] = s | ((d & 63) << 17);
    }
}

// per-bucket local counting sort -> exact per-node CSR (src_srt, offs) + dis
__global__ __launch_bounds__(256) void lsort_kernel(
        const int* __restrict__ boffs, const int* __restrict__ packed,
        int* __restrict__ offs, int* __restrict__ src_srt, float* __restrict__ dis) {
    __shared__ int cnt[BNODES];
    int b   = blockIdx.x;
    int tid = threadIdx.x;
    int beg = boffs[b];
    int end = boffs[b + 1];
    if (tid < BNODES) cnt[tid] = 0;
    __syncthreads();
    for (int i = beg + tid; i < end; i += 256)
        atomicAdd(&cnt[(packed[i] >> 17) & 63], 1);
    __syncthreads();
    if (tid < 64) {                      // wave 0: exclusive scan of 64 counters
        int v = cnt[tid];
        int x = v;
        #pragma unroll
        for (int d = 1; d < 64; d <<= 1) {
            int y = __shfl_up(x, d);
            if (tid >= d) x += y;
        }
        int ex = x - v;                  // exclusive prefix
        int node = (b << BSHIFT) + tid;
        if (node <= NUM_NODES) offs[node] = beg + ex;   // bucket 1562/tid 32 writes offs[N]=E
        if (node <  NUM_NODES) dis[node] = (v > 0) ? rsqrtf((float)v) : 0.0f;
        cnt[tid] = ex;                   // reuse as local cursor
    }
    __syncthreads();
    for (int i = beg + tid; i < end; i += 256) {
        int p  = packed[i];
        int pos = beg + atomicAdd(&cnt[(p >> 17) & 63], 1);
        src_srt[pos] = p & SRC_MASK;
    }
}

// y = dis ⊙ emb (row-wise scale), float4 vectorized
__global__ void prescale_kernel(const float4* __restrict__ emb4, const float* __restrict__ dis,
                                float4* __restrict__ y4) {
    int i = blockIdx.x * blockDim.x + threadIdx.x;
    int stride = gridDim.x * blockDim.x;
    const int n4 = NUM_NODES * EMB_DIM / 4;
    for (; i < n4; i += stride) {
        float d = dis[i >> 4];               // 16 float4s per row
        float4 v = emb4[i];
        v.x *= d; v.y *= d; v.z *= d; v.w *= d;
        y4[i] = v;
    }
}

// ---------------------------------------------------------------------------
// Wave per node, lane = dim, exact CSR gather, zero atomics, y-space.
// Software-pipelined: next iteration's 8 src indices are loaded before this
// iteration's gathers are consumed. All streaming traffic is nontemporal so
// the 4 MB/XCD L2 stays reserved for yin row reuse.
//  mode 0: yout = dn*dn*acc; outw = alpha*(emb + dn*acc)
//  mode 1: yout = dn*dn*acc; outw += alpha*dn*acc
//  mode 2:                   outw += alpha*dn*acc
__global__ __launch_bounds__(256) void prop_kernel(
        const int* __restrict__ offs, const int* __restrict__ src_s,
        const float* __restrict__ dis, const float* __restrict__ yin,
        float* __restrict__ yout, const float* __restrict__ emb,
        float* __restrict__ outw, float alpha, int mode) {
    int wid  = (blockIdx.x * blockDim.x + threadIdx.x) >> 6;
    int lane = threadIdx.x & 63;
    if (wid >= NUM_NODES) return;
    int beg = offs[wid];
    int end = offs[wid + 1];
    float acc = 0.0f;
    int j = beg;

    if (j + 16 <= end) {
        // prologue: load first 8 indices
        int s0 = src_s[j + 0], s1 = src_s[j + 1], s2 = src_s[j + 2], s3 = src_s[j + 3];
        int s4 = src_s[j + 4], s5 = src_s[j + 5], s6 = src_s[j + 6], s7 = src_s[j + 7];
        for (; j + 16 <= end; j += 8) {
            // prefetch next 8 indices (independent of current gathers)
            int t0 = src_s[j + 8],  t1 = src_s[j + 9],
                t2 = src_s[j + 10], t3 = src_s[j + 11];
            int t4 = src_s[j + 12], t5 = src_s[j + 13],
                t6 = src_s[j + 14], t7 = src_s[j + 15];
            float v0 = yin[(s0 << 6) + lane];
            float v1 = yin[(s1 << 6) + lane];
            float v2 = yin[(s2 << 6) + lane];
            float v3 = yin[(s3 << 6) + lane];
            float v4 = yin[(s4 << 6) + lane];
            float v5 = yin[(s5 << 6) + lane];
            float v6 = yin[(s6 << 6) + lane];
            float v7 = yin[(s7 << 6) + lane];
            acc += ((v0 + v1) + (v2 + v3)) + ((v4 + v5) + (v6 + v7));
            s0 = t0; s1 = t1; s2 = t2; s3 = t3;
            s4 = t4; s5 = t5; s6 = t6; s7 = t7;
        }
        // drain the pipelined 8
        float v0 = yin[(s0 << 6) + lane];
        float v1 = yin[(s1 << 6) + lane];
        float v2 = yin[(s2 << 6) + lane];
        float v3 = yin[(s3 << 6) + lane];
        float v4 = yin[(s4 << 6) + lane];
        float v5 = yin[(s5 << 6) + lane];
        float v6 = yin[(s6 << 6) + lane];
        float v7 = yin[(s7 << 6) + lane];
        acc += ((v0 + v1) + (v2 + v3)) + ((v4 + v5) + (v6 + v7));
        j += 8;
    }
    // 8..15 leftover: one unpipelined 8-wide block
    if (j + 8 <= end) {
        int s0 = src_s[j + 0], s1 = src_s[j + 1], s2 = src_s[j + 2], s3 = src_s[j + 3];
        int s4 = src_s[j + 4], s5 = src_s[j + 5], s6 = src_s[j + 6], s7 = src_s[j + 7];
        float v0 = yin[(s0 << 6) + lane];
        float v1 = yin[(s1 << 6) + lane];
        float v2 = yin[(s2 << 6) + lane];
        float v3 = yin[(s3 << 6) + lane];
        float v4 = yin[(s4 << 6) + lane];
        float v5 = yin[(s5 << 6) + lane];
        float v6 = yin[(s6 << 6) + lane];
        float v7 = yin[(s7 << 6) + lane];
        acc += ((v0 + v1) + (v2 + v3)) + ((v4 + v5) + (v6 + v7));
        j += 8;
    }
    for (; j < end; ++j) acc += yin[(src_s[j] << 6) + lane];

    float dn = dis[wid];
    float x  = dn * acc;                 // x_{l+1}
    int o = (wid << 6) + lane;
    if (mode == 0) {
        __builtin_nontemporal_store(dn * x, &yout[o]);
        float e = __builtin_nontemporal_load(&emb[o]);
        __builtin_nontemporal_store(alpha * (e + x), &outw[o]);
    } else if (mode == 1) {
        __builtin_nontemporal_store(dn * x, &yout[o]);
        float w = __builtin_nontemporal_load(&outw[o]);
        __builtin_nontemporal_store(w + alpha * x, &outw[o]);
    } else {
        float w = __builtin_nontemporal_load(&outw[o]);
        __builtin_nontemporal_store(w + alpha * x, &outw[o]);
    }
}

// 16 queries per wave, 4 lanes per query, float4 row loads.
// Lane group g=lane>>2 owns query q = wave*16+g; k=lane&3 walks the row.
__global__ __launch_bounds__(256) void score_kernel(
        const int* __restrict__ qa, const int* __restrict__ qb,
        const float4* __restrict__ x4, float* __restrict__ res) {
    int wave = (blockIdx.x * blockDim.x + threadIdx.x) >> 6;
    int lane = threadIdx.x & 63;
    int g = lane >> 2;                   // query slot in wave (0..15)
    int k = lane & 3;                    // chunk lane (0..3)
    int q = (wave << 4) + g;
    int a = __builtin_nontemporal_load(&qa[q]);
    int b = __builtin_nontemporal_load(&qb[q]);
    const float4* pa = x4 + (a << 4);    // 16 float4s per row
    const float4* pb = x4 + (b << 4);
    float4 a0 = pa[k];      float4 b0 = pb[k];
    float4 a1 = pa[4 + k];  float4 b1 = pb[4 + k];
    float4 a2 = pa[8 + k];  float4 b2 = pb[8 + k];
    float4 a3 = pa[12 + k]; float4 b3 = pb[12 + k];
    float p = a0.x * b0.x;
    p = fmaf(a0.y, b0.y, p); p = fmaf(a0.z, b0.z, p); p = fmaf(a0.w, b0.w, p);
    p = fmaf(a1.x, b1.x, p); p = fmaf(a1.y, b1.y, p);
    p = fmaf(a1.z, b1.z, p); p = fmaf(a1.w, b1.w, p);
    p = fmaf(a2.x, b2.x, p); p = fmaf(a2.y, b2.y, p);
    p = fmaf(a2.z, b2.z, p); p = fmaf(a2.w, b2.w, p);
    p = fmaf(a3.x, b3.x, p); p = fmaf(a3.y, b3.y, p);
    p = fmaf(a3.z, b3.z, p); p = fmaf(a3.w, b3.w, p);
    p += __shfl_xor(p, 1);
    p += __shfl_xor(p, 2);
    if (k == 0) __builtin_nontemporal_store(p, &res[q]);
}

extern "C" void kernel_launch(void* const* d_in, const int* in_sizes, int n_in,
                              void* d_out, int out_size, void* d_ws, size_t ws_size,
                              hipStream_t stream) {
    const float* emb  = (const float*)d_in[0];
    const int*   edge = (const int*)d_in[1];   // [2][NUM_EDGES]: src then dst
    const int*   qidx = (const int*)d_in[2];   // [2][NUM_QUERY]
    float*       out  = (float*)d_out;         // [NUM_QUERY]

    const int* e_src = edge;
    const int* e_dst = edge + NUM_EDGES;
    const int* q_a   = qidx;
    const int* q_b   = qidx + NUM_QUERY;

    const size_t XBYTES = (size_t)NUM_NODES * EMB_DIM * sizeof(float); // 25.6 MB
    char* ws = (char*)d_ws;
    size_t off = 0;
    auto carve = [&](size_t bytes) { void* p = ws + off; off += (bytes + 255) & ~(size_t)255; return p; };
    int*   hist_g  = (int*)  carve((size_t)NCHUNK * NBUCKETS * 4);   // 800 KB
    int*   bcnt    = (int*)  carve((size_t)NBUCKETS * 4);
    int*   boffs   = (int*)  carve((size_t)(NBUCKETS + 1) * 4);
    int*   offs    = (int*)  carve((size_t)(NUM_NODES + 1) * 4);
    float* dis     = (float*)carve((size_t)NUM_NODES * 4);
    int*   packed  = (int*)  carve((size_t)NUM_EDGES * 4);   // 12.8 MB
    int*   src_srt = (int*)  carve((size_t)NUM_EDGES * 4);   // 12.8 MB
    float* yA      = (float*)carve(XBYTES);
    float* yB      = (float*)carve(XBYTES);
    float* outw    = (float*)carve(XBYTES);

    const float alpha = 1.0f / (NUM_LAYERS + 1);   // 0.25

    // ---- build exact dst-sorted CSR: chunked counting sort, zero global atomics
    chist_kernel<<<NCHUNK, 256, 0, stream>>>(e_dst, hist_g);
    bscan_kernel<<<(NBUCKETS * 64 + 255) / 256, 256, 0, stream>>>(hist_g, bcnt);
    scan_kernel<<<1, 1024, 0, stream>>>(bcnt, boffs);
    cscatter_kernel<<<NCHUNK, 256, 0, stream>>>(e_src, e_dst, boffs, hist_g, packed);
    lsort_kernel<<<NBUCKETS, 256, 0, stream>>>(boffs, packed, offs, src_srt, dis);
    prescale_kernel<<<2048, 256, 0, stream>>>((const float4*)emb, dis, (float4*)yA);

    // ---- 3 propagation layers (y-space), out-accumulation fused
    const int PROP_BLOCKS = (NUM_NODES * 64 + 255) / 256;
    prop_kernel<<<PROP_BLOCKS, 256, 0, stream>>>(offs, src_srt, dis, yA, yB, emb, outw, alpha, 0);
    prop_kernel<<<PROP_BLOCKS, 256, 0, stream>>>(offs, src_srt, dis, yB, yA, emb, outw, alpha, 1);
    prop_kernel<<<PROP_BLOCKS, 256, 0, stream>>>(offs, src_srt, dis, yA, yB, emb, outw, alpha, 2);

    // ---- scoring: 64 queries per 256-thread block (16 per wave)
    score_kernel<<<NUM_QUERY / 64, 256, 0, stream>>>(q_a, q_b, (const float4*)outw, out);
}